// Round 3
// baseline (361.396 us; speedup 1.0000x reference)
//
#include <hip/hip_runtime.h>

// Problem: B=512, T=256, C=384, HS=64.  out = softmax(tril(tanh(x@Ws))) @ (x@Wv)
// with Ws = Wq@Wql + Wk@Wkl (elementwise add of q_w,k_w collapses: both linear in x).
//
// R2 structure: barrier-free phase 1. Wave w owns row-tiles {w, 15-w} (balanced
// causal work: (w+1)+(16-w)=17 S-tiles each). A-frags straight from global x
// (fp32->bf16), B-frags straight from L2-resident frag-ordered W blob. LDS only
// for V exchange + per-wave P transpose scratch. ONE __syncthreads per kernel.
#define BATCH 512
#define TT    256
#define CC    384
#define HH    64

typedef float  f32x4 __attribute__((ext_vector_type(4)));
typedef short  s16x8 __attribute__((ext_vector_type(8)));

// LDS map (bytes): Vb 32 KB | per-wave scratch 12 KB * 8
#define VB_OFF    0
#define SCR_OFF   32768
#define LDS_TOTAL 131072

__device__ __forceinline__ unsigned short f2bf(float f) {
    union { float f; unsigned u; } c; c.f = f;
    unsigned u = c.u;
    u += 0x7fffu + ((u >> 16) & 1u);   // RNE
    return (unsigned short)(u >> 16);
}

__device__ __forceinline__ s16x8 cvt8(float4 f0, float4 f1) {
    s16x8 v;
    v[0] = (short)f2bf(f0.x); v[1] = (short)f2bf(f0.y);
    v[2] = (short)f2bf(f0.z); v[3] = (short)f2bf(f0.w);
    v[4] = (short)f2bf(f1.x); v[5] = (short)f2bf(f1.y);
    v[6] = (short)f2bf(f1.z); v[7] = (short)f2bf(f1.w);
    return v;
}

// ---------------- Kernel A: build bf16 weight blob in ws ----------------
// Blob: [kk2 12][ct 20][lane 64][j 8] bf16.  Element (k in [0,384), n in [0,320)):
//   kk2=k>>5, ct=n>>4, lane=((k>>3)&3)*16 + (n&15), j=k&7.
// ct 0..15 = Ws^T (B-frag order), ct 16..19 = Wv^T.
__global__ void prep_w(const float* __restrict__ Wq, const float* __restrict__ Wk,
                       const float* __restrict__ Wv, const float* __restrict__ Wql,
                       const float* __restrict__ Wkl, unsigned short* __restrict__ wsW) {
    int gid = blockIdx.x * 256 + threadIdx.x;   // covers 384*256 + 384*64 = 122880
    int k, n; float val;
    if (gid < CC * 256) {
        k = gid >> 8; int s = gid & 255; n = s;
        float acc = 0.f;
        for (int h = 0; h < HH; ++h)
            acc += Wq[k * HH + h] * Wql[h * 256 + s] + Wk[k * HH + h] * Wkl[h * 256 + s];
        val = acc;
    } else {
        int g2 = gid - CC * 256;
        k = g2 >> 6; int h = g2 & 63; n = 256 + h;
        val = Wv[k * HH + h];
    }
    int kk2 = k >> 5, ct = n >> 4;
    int lane = ((k >> 3) & 3) * 16 + (n & 15);
    int j = k & 7;
    wsW[(((kk2 * 20 + ct) * 64) + lane) * 8 + j] = f2bf(val);
}

// ---------------- Kernel B: per-batch fused attention ----------------
__global__ __launch_bounds__(512, 2) void head_main(const float* __restrict__ x,
                                                    const unsigned short* __restrict__ wsW,
                                                    float* __restrict__ out) {
    extern __shared__ char sm[];
    unsigned short* Vb  = (unsigned short*)(sm + VB_OFF);

    const int t    = threadIdx.x;
    const int w    = (t >> 6) & 7;
    const int lane = t & 63;
    const int q    = lane >> 4;
    const int cidx = lane & 15;
    const int rt0  = w;          // <= 7
    const int rt1  = 15 - w;     // >= 8
    unsigned short* scr = (unsigned short*)(sm + SCR_OFF + w * 12288); // 12KB/wave

    const float* xb  = x + (size_t)blockIdx.x * (TT * CC);
    // A-frag source rows: lane holds row rt*16+(lane&15), cols kk*32 + q*8 .. +8
    const float* xa0 = xb + (rt0 * 16 + cidx) * CC + q * 8;
    const float* xa1 = xb + (rt1 * 16 + cidx) * CC + q * 8;

    // ======== V-pass: accV = x_rows @ Wv (barrier-free) ========
    f32x4 accV[2][4];
#pragma unroll
    for (int i = 0; i < 2; ++i)
#pragma unroll
        for (int j = 0; j < 4; ++j) accV[i][j] = (f32x4){0.f,0.f,0.f,0.f};
    {
        float4 p00 = *(const float4*)(xa0),     p01 = *(const float4*)(xa0 + 4);
        float4 p10 = *(const float4*)(xa1),     p11 = *(const float4*)(xa1 + 4);
        for (int kk = 0; kk < 12; ++kk) {
            s16x8 a0 = cvt8(p00, p01), a1 = cvt8(p10, p11);
            if (kk < 11) {
                const float* n0 = xa0 + (kk + 1) * 32;
                const float* n1 = xa1 + (kk + 1) * 32;
                p00 = *(const float4*)(n0); p01 = *(const float4*)(n0 + 4);
                p10 = *(const float4*)(n1); p11 = *(const float4*)(n1 + 4);
            }
            const unsigned short* wb = wsW + (size_t)kk * 10240 + 16 * 512 + lane * 8;
            s16x8 b0 = *(const s16x8*)(wb);
            s16x8 b1 = *(const s16x8*)(wb + 512);
            s16x8 b2 = *(const s16x8*)(wb + 1024);
            s16x8 b3 = *(const s16x8*)(wb + 1536);
            accV[0][0] = __builtin_amdgcn_mfma_f32_16x16x32_bf16(a0, b0, accV[0][0], 0, 0, 0);
            accV[1][0] = __builtin_amdgcn_mfma_f32_16x16x32_bf16(a1, b0, accV[1][0], 0, 0, 0);
            accV[0][1] = __builtin_amdgcn_mfma_f32_16x16x32_bf16(a0, b1, accV[0][1], 0, 0, 0);
            accV[1][1] = __builtin_amdgcn_mfma_f32_16x16x32_bf16(a1, b1, accV[1][1], 0, 0, 0);
            accV[0][2] = __builtin_amdgcn_mfma_f32_16x16x32_bf16(a0, b2, accV[0][2], 0, 0, 0);
            accV[1][2] = __builtin_amdgcn_mfma_f32_16x16x32_bf16(a1, b2, accV[1][2], 0, 0, 0);
            accV[0][3] = __builtin_amdgcn_mfma_f32_16x16x32_bf16(a0, b3, accV[0][3], 0, 0, 0);
            accV[1][3] = __builtin_amdgcn_mfma_f32_16x16x32_bf16(a1, b3, accV[1][3], 0, 0, 0);
        }
    }
    // publish V to LDS (B-frag order for PV): rows owned by this wave only
#pragma unroll
    for (int ri = 0; ri < 2; ++ri) {
        const int rt = ri ? rt1 : rt0;
#pragma unroll
        for (int vct = 0; vct < 4; ++vct)
#pragma unroll
            for (int rg = 0; rg < 4; ++rg) {
                int srow = rt * 16 + q * 4 + rg;   // C-layout: row = quad*4 + reg
                Vb[((vct * 8 + (srow >> 5)) * 64 + ((srow >> 3) & 3) * 16 + cidx) * 8 + (srow & 7)] =
                    f2bf(accV[ri][vct][rg]);
            }
    }

    // ======== S-pass: accS = x_rows @ Ws, causal-trimmed in groups of 4 tiles ========
    f32x4 accS1[16], accS0[8];
#pragma unroll
    for (int i = 0; i < 16; ++i) accS1[i] = (f32x4){0.f,0.f,0.f,0.f};
#pragma unroll
    for (int i = 0; i < 8; ++i)  accS0[i] = (f32x4){0.f,0.f,0.f,0.f};

    const bool ng4   = (rt1 >= 12);   // waves 0..3 need 4 S-groups, else 3
    const bool g0two = (rt0 >= 4);    // waves 4..7 need 2 groups for rt0
    {
        float4 p00 = *(const float4*)(xa0),     p01 = *(const float4*)(xa0 + 4);
        float4 p10 = *(const float4*)(xa1),     p11 = *(const float4*)(xa1 + 4);
        for (int kk = 0; kk < 12; ++kk) {
            s16x8 a0 = cvt8(p00, p01), a1 = cvt8(p10, p11);
            if (kk < 11) {
                const float* n0 = xa0 + (kk + 1) * 32;
                const float* n1 = xa1 + (kk + 1) * 32;
                p00 = *(const float4*)(n0); p01 = *(const float4*)(n0 + 4);
                p10 = *(const float4*)(n1); p11 = *(const float4*)(n1 + 4);
            }
            const unsigned short* wb = wsW + (size_t)kk * 10240 + lane * 8;
            s16x8 bfA[4], bfB[4];
#pragma unroll
            for (int i = 0; i < 4; ++i) bfA[i] = *(const s16x8*)(wb + i * 512);
#pragma unroll
            for (int i = 0; i < 4; ++i) bfB[i] = *(const s16x8*)(wb + (4 + i) * 512);
            // group 0 (tiles 0..3): both rows
#pragma unroll
            for (int i = 0; i < 4; ++i) {
                accS1[i] = __builtin_amdgcn_mfma_f32_16x16x32_bf16(a1, bfA[i], accS1[i], 0, 0, 0);
                accS0[i] = __builtin_amdgcn_mfma_f32_16x16x32_bf16(a0, bfA[i], accS0[i], 0, 0, 0);
            }
#pragma unroll
            for (int i = 0; i < 4; ++i) bfA[i] = *(const s16x8*)(wb + (8 + i) * 512);
            // group 1 (tiles 4..7): a1 always; a0 only if rt0>=4 (extra tiles masked later)
#pragma unroll
            for (int i = 0; i < 4; ++i)
                accS1[4 + i] = __builtin_amdgcn_mfma_f32_16x16x32_bf16(a1, bfB[i], accS1[4 + i], 0, 0, 0);
            if (g0two) {
#pragma unroll
                for (int i = 0; i < 4; ++i)
                    accS0[4 + i] = __builtin_amdgcn_mfma_f32_16x16x32_bf16(a0, bfB[i], accS0[4 + i], 0, 0, 0);
            }
            if (ng4) {
#pragma unroll
                for (int i = 0; i < 4; ++i) bfB[i] = *(const s16x8*)(wb + (12 + i) * 512);
            }
            // group 2 (tiles 8..11): a1
#pragma unroll
            for (int i = 0; i < 4; ++i)
                accS1[8 + i] = __builtin_amdgcn_mfma_f32_16x16x32_bf16(a1, bfA[i], accS1[8 + i], 0, 0, 0);
            // group 3 (tiles 12..15): a1, waves 0..3 only
            if (ng4) {
#pragma unroll
                for (int i = 0; i < 4; ++i)
                    accS1[12 + i] = __builtin_amdgcn_mfma_f32_16x16x32_bf16(a1, bfB[i], accS1[12 + i], 0, 0, 0);
            }
        }
    }

    // ======== Epilogue: E = exp(tanh(S)) masked -> A-frags via private scratch ========
    float rs0[4] = {0.f,0.f,0.f,0.f}, rs1[4] = {0.f,0.f,0.f,0.f};
    s16x8 pf0[4], pf1[8];
    const int nch1 = rt1 >> 1;   // 4..7
    const int nch0 = rt0 >> 1;   // 0..3

    // rt1: write all chunks, then read all frags (one lgkm round-trip)
#pragma unroll
    for (int ch = 0; ch < 8; ++ch) {
        if (ch <= nch1) {
#pragma unroll
            for (int sub = 0; sub < 2; ++sub) {
                const int ct = 2 * ch + sub;
                const int gcol = ct * 16 + cidx;
                const int c = sub * 16 + cidx;
#pragma unroll
                for (int rg = 0; rg < 4; ++rg) {
                    const int grow = rt1 * 16 + q * 4 + rg;
                    float e = 0.f;
                    if (ct <= rt1 && gcol <= grow) {
                        float sv = accS1[ct][rg];
                        float ex = __expf(2.f * sv);
                        float th = 1.f - __fdividef(2.f, ex + 1.f);   // tanh
                        e = __expf(th);                                // bounded -> no max-sub
                    }
                    rs1[rg] += e;
                    scr[ch * 512 + ((c >> 3) * 16 + q * 4 + rg) * 8 + (c & 7)] = f2bf(e);
                }
            }
        }
    }
#pragma unroll
    for (int ch = 0; ch < 8; ++ch)
        if (ch <= nch1) pf1[ch] = *(const s16x8*)(scr + ch * 512 + lane * 8);

    // rt0: separate scratch region (+4096 shorts)
#pragma unroll
    for (int ch = 0; ch < 4; ++ch) {
        if (ch <= nch0) {
#pragma unroll
            for (int sub = 0; sub < 2; ++sub) {
                const int ct = 2 * ch + sub;
                const int gcol = ct * 16 + cidx;
                const int c = sub * 16 + cidx;
#pragma unroll
                for (int rg = 0; rg < 4; ++rg) {
                    const int grow = rt0 * 16 + q * 4 + rg;
                    float e = 0.f;
                    if (ct <= rt0 && gcol <= grow) {
                        float sv = accS0[ct][rg];
                        float ex = __expf(2.f * sv);
                        float th = 1.f - __fdividef(2.f, ex + 1.f);
                        e = __expf(th);
                    }
                    rs0[rg] += e;
                    scr[4096 + ch * 512 + ((c >> 3) * 16 + q * 4 + rg) * 8 + (c & 7)] = f2bf(e);
                }
            }
        }
    }
#pragma unroll
    for (int ch = 0; ch < 4; ++ch)
        if (ch <= nch0) pf0[ch] = *(const s16x8*)(scr + 4096 + ch * 512 + lane * 8);

    // rowsums: reduce across the 16 lanes sharing each row
#pragma unroll
    for (int rg = 0; rg < 4; ++rg) {
        float v0 = rs0[rg], v1 = rs1[rg];
        v0 += __shfl_xor(v0, 1); v0 += __shfl_xor(v0, 2);
        v0 += __shfl_xor(v0, 4); v0 += __shfl_xor(v0, 8);
        v1 += __shfl_xor(v1, 1); v1 += __shfl_xor(v1, 2);
        v1 += __shfl_xor(v1, 4); v1 += __shfl_xor(v1, 8);
        rs0[rg] = v0; rs1[rg] = v1;
    }

    __syncthreads();   // the ONLY barrier: Vb visible to all waves

    // ======== Phase 2: out = (E @ V) / rowsum, per-wave ========
    f32x4 acc2[2][4];
#pragma unroll
    for (int i = 0; i < 2; ++i)
#pragma unroll
        for (int j = 0; j < 4; ++j) acc2[i][j] = (f32x4){0.f,0.f,0.f,0.f};

#pragma unroll
    for (int ch = 0; ch < 8; ++ch) {
        if (ch <= nch1) {
            s16x8 vb[4];
#pragma unroll
            for (int vct = 0; vct < 4; ++vct)
                vb[vct] = *(const s16x8*)(Vb + ((vct * 8 + ch) * 64 + lane) * 8);
#pragma unroll
            for (int vct = 0; vct < 4; ++vct)
                acc2[1][vct] = __builtin_amdgcn_mfma_f32_16x16x32_bf16(pf1[ch], vb[vct], acc2[1][vct], 0, 0, 0);
            if (ch < 4 && ch <= nch0) {
#pragma unroll
                for (int vct = 0; vct < 4; ++vct)
                    acc2[0][vct] = __builtin_amdgcn_mfma_f32_16x16x32_bf16(pf0[ch], vb[vct], acc2[0][vct], 0, 0, 0);
            }
        }
    }

    float* ob = out + (size_t)blockIdx.x * (TT * HH);
#pragma unroll
    for (int ri = 0; ri < 2; ++ri) {
        const int rt = ri ? rt1 : rt0;
#pragma unroll
        for (int rg = 0; rg < 4; ++rg) {
            int row = rt * 16 + q * 4 + rg;
            float inv = __fdividef(1.f, ri ? rs1[rg] : rs0[rg]);
#pragma unroll
            for (int vct = 0; vct < 4; ++vct)
                ob[row * HH + vct * 16 + cidx] = acc2[ri][vct][rg] * inv;
        }
    }
}

extern "C" void kernel_launch(void* const* d_in, const int* in_sizes, int n_in,
                              void* d_out, int out_size, void* d_ws, size_t ws_size,
                              hipStream_t stream) {
    const float* x   = (const float*)d_in[0];
    const float* Wq  = (const float*)d_in[1];
    const float* Wk  = (const float*)d_in[2];
    const float* Wv  = (const float*)d_in[3];
    const float* Wql = (const float*)d_in[4];
    const float* Wkl = (const float*)d_in[5];
    unsigned short* wsW = (unsigned short*)d_ws;   // 245760 B blob
    float* out = (float*)d_out;

    prep_w<<<480, 256, 0, stream>>>(Wq, Wk, Wv, Wql, Wkl, wsW);

    hipFuncSetAttribute((const void*)head_main,
                        hipFuncAttributeMaxDynamicSharedMemorySize, LDS_TOTAL);
    head_main<<<BATCH, 512, LDS_TOTAL, stream>>>(x, wsW, out);
}